// Round 3
// baseline (591.382 us; speedup 1.0000x reference)
//
#include <hip/hip_runtime.h>
#include <hip/hip_bf16.h>
#include <math.h>

#define NRAYS 8192

typedef short s16x8 __attribute__((ext_vector_type(8)));
typedef float f32x4 __attribute__((ext_vector_type(4)));

__device__ __forceinline__ unsigned pk2(float a, float b){
  union { __hip_bfloat162 h; unsigned u; } cv;
  cv.h = __float22bfloat162_rn(make_float2(a, b));   // v_cvt_pk_bf16_f32: a->low, b->high
  return cv.u;
}
__device__ __forceinline__ unsigned short f2bf(float x){
  unsigned u = __float_as_uint(x);
  u += 0x7FFF + ((u >> 16) & 1);
  return (unsigned short)(u >> 16);
}
__device__ __forceinline__ float softplusf_(float x){ return (x > 20.f) ? x : log1pf(expf(x)); }
__device__ __forceinline__ float sigmoidf_(float x){ return 1.f / (1.f + expf(-x)); }

// d_ws (ushort): WT1[64][32] @0, WT2[64][64] @2048, WO1[64][64] @6144, WC1[64][64] @10240  (all [out][in])
__global__ void prep_weights(const float* __restrict__ Wt1, const float* __restrict__ Wt2,
                             const float* __restrict__ Wo1, const float* __restrict__ Wc1,
                             unsigned short* __restrict__ ws)
{
  const int i0 = blockIdx.x * blockDim.x + threadIdx.x;
  const int st = gridDim.x * blockDim.x;
  for (int i = i0; i < 2048; i += st){ int n = i >> 5, k = i & 31; ws[i]         = f2bf(Wt1[k * 64 + n]); }
  for (int i = i0; i < 4096; i += st){ int n = i >> 6, k = i & 63; ws[2048 + i]  = f2bf(Wt2[k * 64 + n]); }
  for (int i = i0; i < 4096; i += st){ int n = i >> 6, k = i & 63; ws[6144 + i]  = f2bf(Wo1[k * 64 + n]); }
  for (int i = i0; i < 4096; i += st){ int n = i >> 6, k = i & 63; ws[10240 + i] = f2bf(Wc1[k * 64 + n]); }
}

extern "C" __global__ __launch_bounds__(256, 4)
void lightplane_fwd(const float* __restrict__ origins, const float* __restrict__ dirs,
                    const float* __restrict__ nearv,   const float* __restrict__ farv,
                    const float* __restrict__ grid,
                    const float* __restrict__ Wr,  const float* __restrict__ br,
                    const float* __restrict__ bt1, const float* __restrict__ bt2,
                    const float* __restrict__ bo1,
                    const float* __restrict__ Wo2, const float* __restrict__ bo2,
                    const float* __restrict__ bc1,
                    const float* __restrict__ Wc2, const float* __restrict__ bc2,
                    const unsigned short* __restrict__ ws,
                    float* __restrict__ out)
{
  // per-wave scratch region: 2304 dwords. Views:
  //  - feats staging: 64 rows x 40 shorts (20 dwords) = 1280 dwords
  //  - transform:     64 rows x 36 dwords (cols 0..31 used, +4 pad) = 2304 dwords
  __shared__ float s_scr[4 * 2304];            // 36864 B
  __shared__ float s_enc[2][64];
  __shared__ float s_wtot[2][2];
  __shared__ float s_part[2][2][3];

  const int tid  = threadIdx.x;
  const int lane = tid & 63, wv = tid >> 6;
  const int ln15 = lane & 15, quad = lane >> 4;
  const int r_loc = wv >> 1, hh = wv & 1;      // ray within block, ray-half
  const int ray  = blockIdx.x * 2 + r_loc;
  const int s_idx = hh * 64 + lane;            // sample within ray

  float*          wbase = s_scr + wv * 2304;
  unsigned*       uscr  = (unsigned*)wbase;
  unsigned short* fscr  = (unsigned short*)wbase;

  // ---- per-ray harmonic encoding @ Wr + br (f32, waves 0,1) ----
  if (tid < 128) {
    const int rr = tid >> 6, j = tid & 63;
    const int rg = blockIdx.x * 2 + rr;
    const float ddx = dirs[rg * 3 + 0], ddy = dirs[rg * 3 + 1], ddz = dirs[rg * 3 + 2];
    float h[21]; float f = 1.f;
#pragma unroll
    for (int q = 0; q < 3; ++q) {
      h[q * 3 + 0] = sinf(ddx * f); h[q * 3 + 1] = sinf(ddy * f); h[q * 3 + 2] = sinf(ddz * f);
      h[9 + q * 3 + 0] = cosf(ddx * f); h[9 + q * 3 + 1] = cosf(ddy * f); h[9 + q * 3 + 2] = cosf(ddz * f);
      f *= 2.f;
    }
    h[18] = ddx; h[19] = ddy; h[20] = ddz;
    float a = br[j];
#pragma unroll
    for (int i = 0; i < 21; ++i) a = fmaf(h[i], Wr[i * 64 + j], a);
    s_enc[rr][j] = a;
  }

  // ---- sample point + trilinear gather (fp32), thread's sample = lane ----
  const float dx = dirs[ray * 3 + 0], dy = dirs[ray * 3 + 1], dz = dirs[ray * 3 + 2];
  const float ox = origins[ray * 3 + 0], oy = origins[ray * 3 + 1], oz = origins[ray * 3 + 2];
  const float nr = nearv[ray], fa = farv[ray];
  const float t  = nr + (fa - nr) * ((s_idx + 0.5f) * (1.0f / 128.0f));
  const float px = fmaf(t, dx, ox), py = fmaf(t, dy, oy), pz = fmaf(t, dz, oz);

  const float cx = (px + 1.f) * 63.5f, cy = (py + 1.f) * 63.5f, cz = (pz + 1.f) * 63.5f;
  const float fx0 = floorf(cx), fy0 = floorf(cy), fz0 = floorf(cz);
  const float frx = cx - fx0, fry = cy - fy0, frz = cz - fz0;
  int ix0 = min(max((int)fx0, 0), 127), iy0 = min(max((int)fy0, 0), 127), iz0 = min(max((int)fz0, 0), 127);
  int ix1 = min(ix0 + 1, 127), iy1 = min(iy0 + 1, 127), iz1 = min(iz0 + 1, 127);
  const float wxs[2] = {1.f - frx, frx}, wys[2] = {1.f - fry, fry}, wzs[2] = {1.f - frz, frz};
  const int xi[2] = {ix0, ix1}, yi[2] = {iy0, iy1}, zi[2] = {iz0, iz1};

  float fe[32];
#pragma unroll
  for (int k = 0; k < 32; ++k) fe[k] = 0.f;
#pragma unroll
  for (int a = 0; a < 2; ++a)
#pragma unroll
    for (int b2i = 0; b2i < 2; ++b2i)
#pragma unroll
      for (int c2 = 0; c2 < 2; ++c2) {
        const float wgt = wzs[a] * wys[b2i] * wxs[c2];
        const float4* g4 = (const float4*)(grid + ((size_t)((zi[a] * 128 + yi[b2i]) * 128 + xi[c2])) * 32);
#pragma unroll
        for (int k = 0; k < 8; ++k) {
          float4 g = g4[k];
          fe[4 * k + 0] = fmaf(wgt, g.x, fe[4 * k + 0]);
          fe[4 * k + 1] = fmaf(wgt, g.y, fe[4 * k + 1]);
          fe[4 * k + 2] = fmaf(wgt, g.z, fe[4 * k + 2]);
          fe[4 * k + 3] = fmaf(wgt, g.w, fe[4 * k + 3]);
        }
      }

  // stage feats bf16, row = lane (stride 40 shorts)
  {
    unsigned* frow = uscr + lane * 20;
#pragma unroll
    for (int q = 0; q < 4; ++q) {
      uint4 v;
      v.x = pk2(fe[8 * q + 0], fe[8 * q + 1]); v.y = pk2(fe[8 * q + 2], fe[8 * q + 3]);
      v.z = pk2(fe[8 * q + 4], fe[8 * q + 5]); v.w = pk2(fe[8 * q + 6], fe[8 * q + 7]);
      *(uint4*)(frow + 4 * q) = v;
    }
  }
  __syncthreads();   // s_enc ready (feats staging is wave-local)

  // ---- layer 1: Y^T = WT1 . F^T  (K=32) ----
  s16x8 b1[4];
#pragma unroll
  for (int nt = 0; nt < 4; ++nt)
    b1[nt] = *(const s16x8*)(fscr + (16 * nt + ln15) * 40 + quad * 8);

#pragma unroll
  for (int mt = 0; mt < 4; ++mt) {
    s16x8 a1 = *(const s16x8*)(ws + (16 * mt + ln15) * 32 + quad * 8);
    float4 bb = *(const float4*)(bt1 + 16 * mt + 4 * quad);
    f32x4 acc[4];
#pragma unroll
    for (int nt = 0; nt < 4; ++nt) {
      f32x4 c; c[0] = bb.x; c[1] = bb.y; c[2] = bb.z; c[3] = bb.w;
      acc[nt] = __builtin_amdgcn_mfma_f32_16x16x32_bf16(a1, b1[nt], c, 0, 0, 0);
    }
#pragma unroll
    for (int nt = 0; nt < 4; ++nt) {
      uint2 p;
      p.x = pk2(fmaxf(acc[nt][0], 0.f), fmaxf(acc[nt][1], 0.f));
      p.y = pk2(fmaxf(acc[nt][2], 0.f), fmaxf(acc[nt][3], 0.f));
      *(uint2*)(uscr + (16 * nt + ln15) * 36 + 8 * mt + 2 * quad) = p;
    }
  }
  s16x8 b2[4][2];
#pragma unroll
  for (int nt = 0; nt < 4; ++nt)
#pragma unroll
    for (int ks = 0; ks < 2; ++ks)
      b2[nt][ks] = *(const s16x8*)(uscr + (16 * nt + ln15) * 36 + 16 * ks + 4 * quad);

  // ---- layer 2 pass A: cin = relu(e) + enc -> scratch -> b4 ----
#pragma unroll
  for (int mt = 0; mt < 4; ++mt) {
    float4 bb = *(const float4*)(bt2 + 16 * mt + 4 * quad);
    f32x4 acc[4];
#pragma unroll
    for (int nt = 0; nt < 4; ++nt) { f32x4 c; c[0]=bb.x;c[1]=bb.y;c[2]=bb.z;c[3]=bb.w; acc[nt]=c; }
#pragma unroll
    for (int ks = 0; ks < 2; ++ks) {
      s16x8 a = *(const s16x8*)(ws + 2048 + (16 * mt + ln15) * 64 + ks * 32 + quad * 8);
#pragma unroll
      for (int nt = 0; nt < 4; ++nt)
        acc[nt] = __builtin_amdgcn_mfma_f32_16x16x32_bf16(a, b2[nt][ks], acc[nt], 0, 0, 0);
    }
    float4 en = *(const float4*)(&s_enc[r_loc][16 * mt + 4 * quad]);
#pragma unroll
    for (int nt = 0; nt < 4; ++nt) {
      uint2 p;
      p.x = pk2(fmaxf(acc[nt][0], 0.f) + en.x, fmaxf(acc[nt][1], 0.f) + en.y);
      p.y = pk2(fmaxf(acc[nt][2], 0.f) + en.z, fmaxf(acc[nt][3], 0.f) + en.w);
      *(uint2*)(uscr + (16 * nt + ln15) * 36 + 8 * mt + 2 * quad) = p;
    }
  }
  s16x8 b4[4][2];
#pragma unroll
  for (int nt = 0; nt < 4; ++nt)
#pragma unroll
    for (int ks = 0; ks < 2; ++ks)
      b4[nt][ks] = *(const s16x8*)(uscr + (16 * nt + ln15) * 36 + 16 * ks + 4 * quad);

  // ---- layer 2 pass B (recompute, MFMA is cheap): e -> scratch -> b3 ----
#pragma unroll
  for (int mt = 0; mt < 4; ++mt) {
    float4 bb = *(const float4*)(bt2 + 16 * mt + 4 * quad);
    f32x4 acc[4];
#pragma unroll
    for (int nt = 0; nt < 4; ++nt) { f32x4 c; c[0]=bb.x;c[1]=bb.y;c[2]=bb.z;c[3]=bb.w; acc[nt]=c; }
#pragma unroll
    for (int ks = 0; ks < 2; ++ks) {
      s16x8 a = *(const s16x8*)(ws + 2048 + (16 * mt + ln15) * 64 + ks * 32 + quad * 8);
#pragma unroll
      for (int nt = 0; nt < 4; ++nt)
        acc[nt] = __builtin_amdgcn_mfma_f32_16x16x32_bf16(a, b2[nt][ks], acc[nt], 0, 0, 0);
    }
#pragma unroll
    for (int nt = 0; nt < 4; ++nt) {
      uint2 p;
      p.x = pk2(fmaxf(acc[nt][0], 0.f), fmaxf(acc[nt][1], 0.f));
      p.y = pk2(fmaxf(acc[nt][2], 0.f), fmaxf(acc[nt][3], 0.f));
      *(uint2*)(uscr + (16 * nt + ln15) * 36 + 8 * mt + 2 * quad) = p;
    }
  }
  s16x8 b3[4][2];
#pragma unroll
  for (int nt = 0; nt < 4; ++nt)
#pragma unroll
    for (int ks = 0; ks < 2; ++ks)
      b3[nt][ks] = *(const s16x8*)(uscr + (16 * nt + ln15) * 36 + 16 * ks + 4 * quad);

  // ---- layers 3 (opacity) & 4 (color): per-mt tiles + register head dots ----
  float p_o[4] = {0.f, 0.f, 0.f, 0.f};
  float pc0[4] = {0.f, 0.f, 0.f, 0.f}, pc1[4] = {0.f, 0.f, 0.f, 0.f}, pc2[4] = {0.f, 0.f, 0.f, 0.f};
#pragma unroll
  for (int mt = 0; mt < 4; ++mt) {
    // opacity tile
    {
      float4 bb = *(const float4*)(bo1 + 16 * mt + 4 * quad);
      f32x4 acc[4];
#pragma unroll
      for (int nt = 0; nt < 4; ++nt) { f32x4 c; c[0]=bb.x;c[1]=bb.y;c[2]=bb.z;c[3]=bb.w; acc[nt]=c; }
#pragma unroll
      for (int ks = 0; ks < 2; ++ks) {
        s16x8 a = *(const s16x8*)(ws + 6144 + (16 * mt + ln15) * 64 + ks * 32 + quad * 8);
#pragma unroll
        for (int nt = 0; nt < 4; ++nt)
          acc[nt] = __builtin_amdgcn_mfma_f32_16x16x32_bf16(a, b3[nt][ks], acc[nt], 0, 0, 0);
      }
      float4 wo = *(const float4*)(Wo2 + 16 * mt + 4 * quad);
#pragma unroll
      for (int nt = 0; nt < 4; ++nt)
        p_o[nt] += fmaxf(acc[nt][0], 0.f) * wo.x + fmaxf(acc[nt][1], 0.f) * wo.y +
                   fmaxf(acc[nt][2], 0.f) * wo.z + fmaxf(acc[nt][3], 0.f) * wo.w;
    }
    // color tile
    {
      float4 bb = *(const float4*)(bc1 + 16 * mt + 4 * quad);
      f32x4 acc[4];
#pragma unroll
      for (int nt = 0; nt < 4; ++nt) { f32x4 c; c[0]=bb.x;c[1]=bb.y;c[2]=bb.z;c[3]=bb.w; acc[nt]=c; }
#pragma unroll
      for (int ks = 0; ks < 2; ++ks) {
        s16x8 a = *(const s16x8*)(ws + 10240 + (16 * mt + ln15) * 64 + ks * 32 + quad * 8);
#pragma unroll
        for (int nt = 0; nt < 4; ++nt)
          acc[nt] = __builtin_amdgcn_mfma_f32_16x16x32_bf16(a, b4[nt][ks], acc[nt], 0, 0, 0);
      }
      float wcf[12];
      const float* wc = Wc2 + (16 * mt + 4 * quad) * 3;
      *(float4*)&wcf[0] = ((const float4*)wc)[0];
      *(float4*)&wcf[4] = ((const float4*)wc)[1];
      *(float4*)&wcf[8] = ((const float4*)wc)[2];
#pragma unroll
      for (int nt = 0; nt < 4; ++nt)
#pragma unroll
        for (int r = 0; r < 4; ++r) {
          const float hv = fmaxf(acc[nt][r], 0.f);
          pc0[nt] = fmaf(hv, wcf[r * 3 + 0], pc0[nt]);
          pc1[nt] = fmaf(hv, wcf[r * 3 + 1], pc1[nt]);
          pc2[nt] = fmaf(hv, wcf[r * 3 + 2], pc2[nt]);
        }
    }
  }
  // cross-quad reduce (lanes ln15, +16, +32, +48 hold partials of same samples)
#pragma unroll
  for (int nt = 0; nt < 4; ++nt) {
    p_o[nt] += __shfl_xor(p_o[nt], 16, 64); p_o[nt] += __shfl_xor(p_o[nt], 32, 64);
    pc0[nt] += __shfl_xor(pc0[nt], 16, 64); pc0[nt] += __shfl_xor(pc0[nt], 32, 64);
    pc1[nt] += __shfl_xor(pc1[nt], 16, 64); pc1[nt] += __shfl_xor(pc1[nt], 32, 64);
    pc2[nt] += __shfl_xor(pc2[nt], 16, 64); pc2[nt] += __shfl_xor(pc2[nt], 32, 64);
  }

  const float delta = (fa - nr) * (1.0f / 128.0f);
  const float bo2v = bo2[0], bc2x = bc2[0], bc2y = bc2[1], bc2z = bc2[2];
  float A_[4], C0[4], C1[4], C2[4];
#pragma unroll
  for (int nt = 0; nt < 4; ++nt) {
    const float dens = softplusf_(p_o[nt] + bo2v);
    A_[nt] = 1.f - expf(-delta * dens);
    C0[nt] = sigmoidf_(pc0[nt] + bc2x);
    C1[nt] = sigmoidf_(pc1[nt] + bc2y);
    C2[nt] = sigmoidf_(pc2[nt] + bc2z);
  }
  // own sample: lane = 16*quad' + ln15 -> its sample's nt == quad
  const float a_own = (quad < 2) ? (quad == 0 ? A_[0] : A_[1]) : (quad == 2 ? A_[2] : A_[3]);
  const float c0own = (quad < 2) ? (quad == 0 ? C0[0] : C0[1]) : (quad == 2 ? C0[2] : C0[3]);
  const float c1own = (quad < 2) ? (quad == 0 ? C1[0] : C1[1]) : (quad == 2 ? C1[2] : C1[3]);
  const float c2own = (quad < 2) ? (quad == 0 ? C2[0] : C2[1]) : (quad == 2 ? C2[2] : C2[3]);

  // ---- in-wave inclusive product scan of (1 - alpha), sample = lane ----
  float v = 1.f - a_own;
#pragma unroll
  for (int off = 1; off < 64; off <<= 1) {
    const float u = __shfl_up(v, off, 64);
    if (lane >= off) v *= u;
  }
  const float tot = __shfl(v, 63, 64);
  if (lane == 0) s_wtot[r_loc][hh] = tot;
  float excl = __shfl_up(v, 1, 64);
  if (lane == 0) excl = 1.f;
  __syncthreads();
  const float prefix = hh ? s_wtot[r_loc][0] : 1.f;
  const float Ttot   = s_wtot[r_loc][0] * s_wtot[r_loc][1];
  const float wgt = prefix * excl * a_own;

  // ---- color integral: wave reduce, then combine halves ----
  float p0 = wgt * c0own, p1 = wgt * c1own, p2 = wgt * c2own;
#pragma unroll
  for (int off = 32; off > 0; off >>= 1) {
    p0 += __shfl_down(p0, off, 64);
    p1 += __shfl_down(p1, off, 64);
    p2 += __shfl_down(p2, off, 64);
  }
  if (lane == 0) { s_part[r_loc][hh][0] = p0; s_part[r_loc][hh][1] = p1; s_part[r_loc][hh][2] = p2; }
  __syncthreads();
  if (hh == 0 && lane == 0) {
    out[ray * 3 + 0] = s_part[r_loc][0][0] + s_part[r_loc][1][0];
    out[ray * 3 + 1] = s_part[r_loc][0][1] + s_part[r_loc][1][1];
    out[ray * 3 + 2] = s_part[r_loc][0][2] + s_part[r_loc][1][2];
    out[NRAYS * 3 + ray] = 1.f - Ttot;
  }
}

extern "C" void kernel_launch(void* const* d_in, const int* in_sizes, int n_in,
                              void* d_out, int out_size, void* d_ws, size_t ws_size,
                              hipStream_t stream)
{
  (void)in_sizes; (void)n_in; (void)out_size; (void)ws_size;
  const float* origins = (const float*)d_in[0];
  const float* dirs    = (const float*)d_in[1];
  const float* nearv   = (const float*)d_in[2];
  const float* farv    = (const float*)d_in[3];
  const float* grid    = (const float*)d_in[4];
  const float* Wr  = (const float*)d_in[5];
  const float* br  = (const float*)d_in[6];
  const float* Wt1 = (const float*)d_in[7];
  const float* bt1 = (const float*)d_in[8];
  const float* Wt2 = (const float*)d_in[9];
  const float* bt2 = (const float*)d_in[10];
  const float* Wo1 = (const float*)d_in[11];
  const float* bo1 = (const float*)d_in[12];
  const float* Wo2 = (const float*)d_in[13];
  const float* bo2 = (const float*)d_in[14];
  const float* Wc1 = (const float*)d_in[15];
  const float* bc1 = (const float*)d_in[16];
  const float* Wc2 = (const float*)d_in[17];
  const float* bc2 = (const float*)d_in[18];
  unsigned short* ws = (unsigned short*)d_ws;
  float* out = (float*)d_out;

  prep_weights<<<16, 256, 0, stream>>>(Wt1, Wt2, Wo1, Wc1, ws);
  lightplane_fwd<<<NRAYS / 2, 256, 0, stream>>>(origins, dirs, nearv, farv, grid,
                                                Wr, br, bt1, bt2, bo1, Wo2, bo2,
                                                bc1, Wc2, bc2, ws, out);
}

// Round 4
// 511.542 us; speedup vs baseline: 1.1561x; 1.1561x over previous
//
#include <hip/hip_runtime.h>
#include <hip/hip_bf16.h>
#include <math.h>

#define NRAYS 8192

typedef short s16x8 __attribute__((ext_vector_type(8)));
typedef float f32x4 __attribute__((ext_vector_type(4)));

__device__ __forceinline__ unsigned pk2(float a, float b){
  union { __hip_bfloat162 h; unsigned u; } cv;
  cv.h = __float22bfloat162_rn(make_float2(a, b));   // v_cvt_pk_bf16_f32
  return cv.u;
}
__device__ __forceinline__ unsigned short f2bf(float x){
  unsigned u = __float_as_uint(x);
  u += 0x7FFF + ((u >> 16) & 1);
  return (unsigned short)(u >> 16);
}
__device__ __forceinline__ float bf2f(unsigned short s){ return __uint_as_float(((unsigned)s) << 16); }
__device__ __forceinline__ float softplusf_(float x){ return (x > 20.f) ? x : log1pf(expf(x)); }
__device__ __forceinline__ float sigmoidf_(float x){ return 1.f / (1.f + expf(-x)); }

// d_ws (ushort): WT1[64][32] @0, WT2[64][64] @2048, WO1[64][64] @6144, WC1[64][64] @10240  (all [out][in])
__global__ void prep_weights(const float* __restrict__ Wt1, const float* __restrict__ Wt2,
                             const float* __restrict__ Wo1, const float* __restrict__ Wc1,
                             unsigned short* __restrict__ ws)
{
  const int i0 = blockIdx.x * blockDim.x + threadIdx.x;
  const int st = gridDim.x * blockDim.x;
  for (int i = i0; i < 2048; i += st){ int n = i >> 5, k = i & 31; ws[i]         = f2bf(Wt1[k * 64 + n]); }
  for (int i = i0; i < 4096; i += st){ int n = i >> 6, k = i & 63; ws[2048 + i]  = f2bf(Wt2[k * 64 + n]); }
  for (int i = i0; i < 4096; i += st){ int n = i >> 6, k = i & 63; ws[6144 + i]  = f2bf(Wo1[k * 64 + n]); }
  for (int i = i0; i < 4096; i += st){ int n = i >> 6, k = i & 63; ws[10240 + i] = f2bf(Wc1[k * 64 + n]); }
}

extern "C" __global__ __launch_bounds__(256, 3)
void lightplane_fwd(const float* __restrict__ origins, const float* __restrict__ dirs,
                    const float* __restrict__ nearv,   const float* __restrict__ farv,
                    const float* __restrict__ grid,
                    const float* __restrict__ Wr,  const float* __restrict__ br,
                    const float* __restrict__ bt1, const float* __restrict__ bt2,
                    const float* __restrict__ bo1,
                    const float* __restrict__ Wo2, const float* __restrict__ bo2,
                    const float* __restrict__ bc1,
                    const float* __restrict__ Wc2, const float* __restrict__ bc2,
                    const unsigned short* __restrict__ ws,
                    float* __restrict__ out)
{
  // per-wave scratch: 2304 dwords. Views:
  //  - feats staging: 64 rows x 20 dwords (40 shorts)
  //  - transform:     64 rows x 36 dwords (LDS: row=sample, bf16 col=neuron; +4 dword pad)
  __shared__ float s_scr[4 * 2304];            // 36864 B
  __shared__ float s_enc[2][64];
  __shared__ float s_wtot[2][2];
  __shared__ float s_part[2][2][3];

  const int tid  = threadIdx.x;
  const int lane = tid & 63, wv = tid >> 6;
  const int ln15 = lane & 15, quad = lane >> 4;
  const int r_loc = wv >> 1, hh = wv & 1;      // ray within block, ray-half
  const int ray  = blockIdx.x * 2 + r_loc;
  const int s_idx = hh * 64 + lane;            // sample within ray

  float*          wbase = s_scr + wv * 2304;
  unsigned*       uscr  = (unsigned*)wbase;
  unsigned short* fscr  = (unsigned short*)wbase;

  // ---- per-ray harmonic encoding @ Wr + br (f32, waves 0,1) ----
  if (tid < 128) {
    const int rr = tid >> 6, j = tid & 63;
    const int rg = blockIdx.x * 2 + rr;
    const float ddx = dirs[rg * 3 + 0], ddy = dirs[rg * 3 + 1], ddz = dirs[rg * 3 + 2];
    float h[21]; float f = 1.f;
#pragma unroll
    for (int q = 0; q < 3; ++q) {
      h[q * 3 + 0] = sinf(ddx * f); h[q * 3 + 1] = sinf(ddy * f); h[q * 3 + 2] = sinf(ddz * f);
      h[9 + q * 3 + 0] = cosf(ddx * f); h[9 + q * 3 + 1] = cosf(ddy * f); h[9 + q * 3 + 2] = cosf(ddz * f);
      f *= 2.f;
    }
    h[18] = ddx; h[19] = ddy; h[20] = ddz;
    float a = br[j];
#pragma unroll
    for (int i = 0; i < 21; ++i) a = fmaf(h[i], Wr[i * 64 + j], a);
    s_enc[rr][j] = a;
  }

  // ---- sample point + trilinear gather (fp32), thread's sample = lane ----
  const float dx = dirs[ray * 3 + 0], dy = dirs[ray * 3 + 1], dz = dirs[ray * 3 + 2];
  const float ox = origins[ray * 3 + 0], oy = origins[ray * 3 + 1], oz = origins[ray * 3 + 2];
  const float nr = nearv[ray], fa = farv[ray];
  const float t  = nr + (fa - nr) * ((s_idx + 0.5f) * (1.0f / 128.0f));
  const float px = fmaf(t, dx, ox), py = fmaf(t, dy, oy), pz = fmaf(t, dz, oz);

  const float cx = (px + 1.f) * 63.5f, cy = (py + 1.f) * 63.5f, cz = (pz + 1.f) * 63.5f;
  const float fx0 = floorf(cx), fy0 = floorf(cy), fz0 = floorf(cz);
  const float frx = cx - fx0, fry = cy - fy0, frz = cz - fz0;
  int ix0 = min(max((int)fx0, 0), 127), iy0 = min(max((int)fy0, 0), 127), iz0 = min(max((int)fz0, 0), 127);
  int ix1 = min(ix0 + 1, 127), iy1 = min(iy0 + 1, 127), iz1 = min(iz0 + 1, 127);
  const float wxs[2] = {1.f - frx, frx}, wys[2] = {1.f - fry, fry}, wzs[2] = {1.f - frz, frz};
  const int xi[2] = {ix0, ix1}, yi[2] = {iy0, iy1}, zi[2] = {iz0, iz1};

  float fe[32];
#pragma unroll
  for (int k = 0; k < 32; ++k) fe[k] = 0.f;
#pragma unroll
  for (int a = 0; a < 2; ++a)
#pragma unroll
    for (int b2i = 0; b2i < 2; ++b2i)
#pragma unroll
      for (int c2 = 0; c2 < 2; ++c2) {
        const float wgt = wzs[a] * wys[b2i] * wxs[c2];
        const float4* g4 = (const float4*)(grid + ((size_t)((zi[a] * 128 + yi[b2i]) * 128 + xi[c2])) * 32);
#pragma unroll
        for (int k = 0; k < 8; ++k) {
          float4 g = g4[k];
          fe[4 * k + 0] = fmaf(wgt, g.x, fe[4 * k + 0]);
          fe[4 * k + 1] = fmaf(wgt, g.y, fe[4 * k + 1]);
          fe[4 * k + 2] = fmaf(wgt, g.z, fe[4 * k + 2]);
          fe[4 * k + 3] = fmaf(wgt, g.w, fe[4 * k + 3]);
        }
      }

  // stage feats bf16, row = lane (20 dwords stride)
  {
    unsigned* frow = uscr + lane * 20;
#pragma unroll
    for (int q = 0; q < 4; ++q) {
      uint4 v;
      v.x = pk2(fe[8 * q + 0], fe[8 * q + 1]); v.y = pk2(fe[8 * q + 2], fe[8 * q + 3]);
      v.z = pk2(fe[8 * q + 4], fe[8 * q + 5]); v.w = pk2(fe[8 * q + 6], fe[8 * q + 7]);
      *(uint4*)(frow + 4 * q) = v;
    }
  }
  __syncthreads();   // s_enc ready (feats staging is wave-local)

  // ---- layer 1: Y^T = WT1 . F^T  (K=32) ----
  s16x8 b1[4];
#pragma unroll
  for (int nt = 0; nt < 4; ++nt)
    b1[nt] = *(const s16x8*)(fscr + (16 * nt + ln15) * 40 + quad * 8);

#pragma unroll
  for (int mt = 0; mt < 4; ++mt) {
    s16x8 a1 = *(const s16x8*)(ws + (16 * mt + ln15) * 32 + quad * 8);
    float4 bb = *(const float4*)(bt1 + 16 * mt + 4 * quad);
    f32x4 acc[4];
#pragma unroll
    for (int nt = 0; nt < 4; ++nt) {
      f32x4 c; c[0] = bb.x; c[1] = bb.y; c[2] = bb.z; c[3] = bb.w;
      acc[nt] = __builtin_amdgcn_mfma_f32_16x16x32_bf16(a1, b1[nt], c, 0, 0, 0);
    }
#pragma unroll
    for (int nt = 0; nt < 4; ++nt) {
      uint2 p;
      p.x = pk2(fmaxf(acc[nt][0], 0.f), fmaxf(acc[nt][1], 0.f));
      p.y = pk2(fmaxf(acc[nt][2], 0.f), fmaxf(acc[nt][3], 0.f));
      *(uint2*)(uscr + (16 * nt + ln15) * 36 + 8 * mt + 2 * quad) = p;
    }
  }
  s16x8 b2[4][2];
#pragma unroll
  for (int nt = 0; nt < 4; ++nt)
#pragma unroll
    for (int ks = 0; ks < 2; ++ks)
      b2[nt][ks] = *(const s16x8*)(uscr + (16 * nt + ln15) * 36 + 16 * ks + 4 * quad);

  // ---- layer 2: e = relu(h1 @ Wt2 + bt2) -> b3 (b2 dies here) ----
#pragma unroll
  for (int mt = 0; mt < 4; ++mt) {
    float4 bb = *(const float4*)(bt2 + 16 * mt + 4 * quad);
    f32x4 acc[4];
#pragma unroll
    for (int nt = 0; nt < 4; ++nt) { f32x4 c; c[0]=bb.x;c[1]=bb.y;c[2]=bb.z;c[3]=bb.w; acc[nt]=c; }
#pragma unroll
    for (int ks = 0; ks < 2; ++ks) {
      s16x8 a = *(const s16x8*)(ws + 2048 + (16 * mt + ln15) * 64 + ks * 32 + quad * 8);
#pragma unroll
      for (int nt = 0; nt < 4; ++nt)
        acc[nt] = __builtin_amdgcn_mfma_f32_16x16x32_bf16(a, b2[nt][ks], acc[nt], 0, 0, 0);
    }
#pragma unroll
    for (int nt = 0; nt < 4; ++nt) {
      uint2 p;
      p.x = pk2(fmaxf(acc[nt][0], 0.f), fmaxf(acc[nt][1], 0.f));
      p.y = pk2(fmaxf(acc[nt][2], 0.f), fmaxf(acc[nt][3], 0.f));
      *(uint2*)(uscr + (16 * nt + ln15) * 36 + 8 * mt + 2 * quad) = p;
    }
  }
  s16x8 b3[4][2];
#pragma unroll
  for (int nt = 0; nt < 4; ++nt)
#pragma unroll
    for (int ks = 0; ks < 2; ++ks)
      b3[nt][ks] = *(const s16x8*)(uscr + (16 * nt + ln15) * 36 + 16 * ks + 4 * quad);

  // ---- opacity branch: relu(e@Wo1+bo1) dot Wo2 (consumes b3, acc per mt) ----
  float p_o[4] = {0.f, 0.f, 0.f, 0.f};
#pragma unroll
  for (int mt = 0; mt < 4; ++mt) {
    float4 bb = *(const float4*)(bo1 + 16 * mt + 4 * quad);
    f32x4 acc[4];
#pragma unroll
    for (int nt = 0; nt < 4; ++nt) { f32x4 c; c[0]=bb.x;c[1]=bb.y;c[2]=bb.z;c[3]=bb.w; acc[nt]=c; }
#pragma unroll
    for (int ks = 0; ks < 2; ++ks) {
      s16x8 a = *(const s16x8*)(ws + 6144 + (16 * mt + ln15) * 64 + ks * 32 + quad * 8);
#pragma unroll
      for (int nt = 0; nt < 4; ++nt)
        acc[nt] = __builtin_amdgcn_mfma_f32_16x16x32_bf16(a, b3[nt][ks], acc[nt], 0, 0, 0);
    }
    float4 wo = *(const float4*)(Wo2 + 16 * mt + 4 * quad);
#pragma unroll
    for (int nt = 0; nt < 4; ++nt)
      p_o[nt] += fmaxf(acc[nt][0], 0.f) * wo.x + fmaxf(acc[nt][1], 0.f) * wo.y +
                 fmaxf(acc[nt][2], 0.f) * wo.z + fmaxf(acc[nt][3], 0.f) * wo.w;
  }

  // ---- derive color-input frags IN PLACE: b3 <- bf16(e + enc) ----
#pragma unroll
  for (int ks = 0; ks < 2; ++ks) {
    const float* ep = &s_enc[r_loc][ks * 32 + quad * 8];
    float4 e0 = *(const float4*)ep;
    float4 e1 = *(const float4*)(ep + 4);
    const float encv[8] = {e0.x, e0.y, e0.z, e0.w, e1.x, e1.y, e1.z, e1.w};
#pragma unroll
    for (int nt = 0; nt < 4; ++nt) {
      s16x8 v = b3[nt][ks];
      s16x8 r;
#pragma unroll
      for (int j = 0; j < 8; ++j)
        r[j] = (short)f2bf(bf2f((unsigned short)v[j]) + encv[j]);
      b3[nt][ks] = r;
    }
  }

  // ---- color branch: relu(cin@Wc1+bc1) dot Wc2 ----
  float pc0[4] = {0.f, 0.f, 0.f, 0.f}, pc1[4] = {0.f, 0.f, 0.f, 0.f}, pc2[4] = {0.f, 0.f, 0.f, 0.f};
#pragma unroll
  for (int mt = 0; mt < 4; ++mt) {
    float4 bb = *(const float4*)(bc1 + 16 * mt + 4 * quad);
    f32x4 acc[4];
#pragma unroll
    for (int nt = 0; nt < 4; ++nt) { f32x4 c; c[0]=bb.x;c[1]=bb.y;c[2]=bb.z;c[3]=bb.w; acc[nt]=c; }
#pragma unroll
    for (int ks = 0; ks < 2; ++ks) {
      s16x8 a = *(const s16x8*)(ws + 10240 + (16 * mt + ln15) * 64 + ks * 32 + quad * 8);
#pragma unroll
      for (int nt = 0; nt < 4; ++nt)
        acc[nt] = __builtin_amdgcn_mfma_f32_16x16x32_bf16(a, b3[nt][ks], acc[nt], 0, 0, 0);
    }
    float wcf[12];
    const float* wc = Wc2 + (16 * mt + 4 * quad) * 3;
    *(float4*)&wcf[0] = ((const float4*)wc)[0];
    *(float4*)&wcf[4] = ((const float4*)wc)[1];
    *(float4*)&wcf[8] = ((const float4*)wc)[2];
#pragma unroll
    for (int nt = 0; nt < 4; ++nt)
#pragma unroll
      for (int r = 0; r < 4; ++r) {
        const float hv = fmaxf(acc[nt][r], 0.f);
        pc0[nt] = fmaf(hv, wcf[r * 3 + 0], pc0[nt]);
        pc1[nt] = fmaf(hv, wcf[r * 3 + 1], pc1[nt]);
        pc2[nt] = fmaf(hv, wcf[r * 3 + 2], pc2[nt]);
      }
  }

  // cross-quad reduce (k-split partials of the same samples)
#pragma unroll
  for (int nt = 0; nt < 4; ++nt) {
    p_o[nt] += __shfl_xor(p_o[nt], 16, 64); p_o[nt] += __shfl_xor(p_o[nt], 32, 64);
    pc0[nt] += __shfl_xor(pc0[nt], 16, 64); pc0[nt] += __shfl_xor(pc0[nt], 32, 64);
    pc1[nt] += __shfl_xor(pc1[nt], 16, 64); pc1[nt] += __shfl_xor(pc1[nt], 32, 64);
    pc2[nt] += __shfl_xor(pc2[nt], 16, 64); pc2[nt] += __shfl_xor(pc2[nt], 32, 64);
  }

  const float delta = (fa - nr) * (1.0f / 128.0f);
  const float bo2v = bo2[0], bc2x = bc2[0], bc2y = bc2[1], bc2z = bc2[2];
  float A_[4], C0[4], C1[4], C2[4];
#pragma unroll
  for (int nt = 0; nt < 4; ++nt) {
    const float dens = softplusf_(p_o[nt] + bo2v);
    A_[nt] = 1.f - expf(-delta * dens);
    C0[nt] = sigmoidf_(pc0[nt] + bc2x);
    C1[nt] = sigmoidf_(pc1[nt] + bc2y);
    C2[nt] = sigmoidf_(pc2[nt] + bc2z);
  }
  // own sample: lane = 16*quad + ln15 -> nt == quad
  const float a_own = (quad < 2) ? (quad == 0 ? A_[0] : A_[1]) : (quad == 2 ? A_[2] : A_[3]);
  const float c0own = (quad < 2) ? (quad == 0 ? C0[0] : C0[1]) : (quad == 2 ? C0[2] : C0[3]);
  const float c1own = (quad < 2) ? (quad == 0 ? C1[0] : C1[1]) : (quad == 2 ? C1[2] : C1[3]);
  const float c2own = (quad < 2) ? (quad == 0 ? C2[0] : C2[1]) : (quad == 2 ? C2[2] : C2[3]);

  // ---- in-wave inclusive product scan of (1 - alpha), sample = lane ----
  float v = 1.f - a_own;
#pragma unroll
  for (int off = 1; off < 64; off <<= 1) {
    const float u = __shfl_up(v, off, 64);
    if (lane >= off) v *= u;
  }
  const float tot = __shfl(v, 63, 64);
  if (lane == 0) s_wtot[r_loc][hh] = tot;
  float excl = __shfl_up(v, 1, 64);
  if (lane == 0) excl = 1.f;
  __syncthreads();
  const float prefix = hh ? s_wtot[r_loc][0] : 1.f;
  const float Ttot   = s_wtot[r_loc][0] * s_wtot[r_loc][1];
  const float wgt = prefix * excl * a_own;

  // ---- color integral: wave reduce, then combine halves ----
  float p0 = wgt * c0own, p1 = wgt * c1own, p2 = wgt * c2own;
#pragma unroll
  for (int off = 32; off > 0; off >>= 1) {
    p0 += __shfl_down(p0, off, 64);
    p1 += __shfl_down(p1, off, 64);
    p2 += __shfl_down(p2, off, 64);
  }
  if (lane == 0) { s_part[r_loc][hh][0] = p0; s_part[r_loc][hh][1] = p1; s_part[r_loc][hh][2] = p2; }
  __syncthreads();
  if (hh == 0 && lane == 0) {
    out[ray * 3 + 0] = s_part[r_loc][0][0] + s_part[r_loc][1][0];
    out[ray * 3 + 1] = s_part[r_loc][0][1] + s_part[r_loc][1][1];
    out[ray * 3 + 2] = s_part[r_loc][0][2] + s_part[r_loc][1][2];
    out[NRAYS * 3 + ray] = 1.f - Ttot;
  }
}

extern "C" void kernel_launch(void* const* d_in, const int* in_sizes, int n_in,
                              void* d_out, int out_size, void* d_ws, size_t ws_size,
                              hipStream_t stream)
{
  (void)in_sizes; (void)n_in; (void)out_size; (void)ws_size;
  const float* origins = (const float*)d_in[0];
  const float* dirs    = (const float*)d_in[1];
  const float* nearv   = (const float*)d_in[2];
  const float* farv    = (const float*)d_in[3];
  const float* grid    = (const float*)d_in[4];
  const float* Wr  = (const float*)d_in[5];
  const float* br  = (const float*)d_in[6];
  const float* Wt1 = (const float*)d_in[7];
  const float* bt1 = (const float*)d_in[8];
  const float* Wt2 = (const float*)d_in[9];
  const float* bt2 = (const float*)d_in[10];
  const float* Wo1 = (const float*)d_in[11];
  const float* bo1 = (const float*)d_in[12];
  const float* Wo2 = (const float*)d_in[13];
  const float* bo2 = (const float*)d_in[14];
  const float* Wc1 = (const float*)d_in[15];
  const float* bc1 = (const float*)d_in[16];
  const float* Wc2 = (const float*)d_in[17];
  const float* bc2 = (const float*)d_in[18];
  unsigned short* ws = (unsigned short*)d_ws;
  float* out = (float*)d_out;

  prep_weights<<<16, 256, 0, stream>>>(Wt1, Wt2, Wo1, Wc1, ws);
  lightplane_fwd<<<NRAYS / 2, 256, 0, stream>>>(origins, dirs, nearv, farv, grid,
                                                Wr, br, bt1, bt2, bo1, Wo2, bo2,
                                                bc1, Wc2, bc2, ws, out);
}